// Round 8
// baseline (510.879 us; speedup 1.0000x reference)
//
#include <hip/hip_runtime.h>

#define CC 19
#define NPOS 361
#define DIM 256
#define TKEY 32
#define NTILES 12

// LDS layout (bytes), SINGLE-buffered, 2 barriers/tile, sized for 2 blocks/CU:
//   sA   : max(sQ 32x264, sP 8x32x40) = 20480  [0)      sQ pre-loop, sP in-loop
//   bufx : 32 x 264 bf16              = 16896  [20480)  x tile; AO in epilogue
//   sK   : 32 x 264 bf16              = 16896  [37376)  K tile; proj in epilogue
//   sVT  : 272 x 40 bf16              = 21760  [54272)  rows 256..271 = ones/zeros
// total = 76032 (<= 80KB -> 2 blocks/CU; VGPR=128 permits 16 waves/CU)
#define LDS_BYTES 76032

using bf16x8 = __attribute__((ext_vector_type(8))) short;
using floatx4 = __attribute__((ext_vector_type(4))) float;

__device__ __forceinline__ unsigned short f2bf(float f) {
  unsigned u = __builtin_bit_cast(unsigned, f);
  u += 0x7fffu + ((u >> 16) & 1u);
  return (unsigned short)(u >> 16);
}

// load 8 consecutive f32 from global, convert to a bf16x8 fragment
__device__ __forceinline__ bf16x8 ld_cvt8(const float* __restrict__ p) {
  const float4 v0 = *(const float4*)p;
  const float4 v1 = *(const float4*)(p + 4);
  bf16x8 r;
  r[0] = (short)f2bf(v0.x); r[1] = (short)f2bf(v0.y);
  r[2] = (short)f2bf(v0.z); r[3] = (short)f2bf(v0.w);
  r[4] = (short)f2bf(v1.x); r[5] = (short)f2bf(v1.y);
  r[6] = (short)f2bf(v1.z); r[7] = (short)f2bf(v1.w);
  return r;
}

// launch_bounds (512,2): targets 2 blocks/CU co-residency -> compiler allocates
// exactly 128 VGPR (R3/R5/R7 evidence), no spills. LDS 76KB makes the second
// block actually fit now.
__launch_bounds__(512, 2)
__global__ void cgca_kernel(const float* __restrict__ xf,
                            const float* __restrict__ w_in,
                            const float* __restrict__ b_in,
                            const float* __restrict__ w_out,
                            const float* __restrict__ b_out,
                            const float* __restrict__ w_fuse,
                            const float* __restrict__ b_fuse,
                            float* __restrict__ out) {
  // XCD-aware swizzle: same channel's 32 batches contiguous on one XCD.
  const int bid = blockIdx.x;
  const int xcd = bid & 7;
  const int slot = bid >> 3;
  int c, b;
  if (slot < 64) {
    c = ((slot >> 5) << 3) + xcd;   // channels 0..15
    b = slot & 31;
  } else {
    const int widx = ((slot - 64) << 3) + xcd;  // 0..95
    c = 16 + (widx >> 5);           // channels 16..18
    b = widx & 31;
  }

  const int tid = threadIdx.x;
  const int w = tid >> 6;        // wave 0..7 == head index
  const int lane = tid & 63;
  const int quad = lane >> 4;
  const int l16 = lane & 15;

  extern __shared__ char smem[];
  unsigned short* sQ   = (unsigned short*)(smem);                 // pre-loop only
  unsigned short* sP   = (unsigned short*)(smem) + w * 1280;      // in-loop, wave-private
  unsigned short* bufx = (unsigned short*)(smem + 20480);
  unsigned short* sK   = (unsigned short*)(smem + 37376);
  unsigned short* sVT  = (unsigned short*)(smem + 54272);

  const float scale = 0.17677669529663687f;  // 1/sqrt(32)
  const floatx4 fzero = {0.f, 0.f, 0.f, 0.f};

  // ones/zero rows 256..271 of sVT (ones-column trick for the softmax denom):
  // row 256 = 1.0, rows 257..271 = 0. K/V stores never touch these rows.
  for (int i = tid; i < 16 * 40; i += 512) {
    const int row = i / 40;
    const int col = i - row * 40;
    sVT[(256 + row) * 40 + col] = (row == 0) ? (unsigned short)0x3F80 : (unsigned short)0;
  }

  // ---------------- Phase 1: Q = xq @ wq^T + bq (scaled) -> sQ bf16 [32][264]
  {
    const int eh0 = w * 32;
#pragma unroll
    for (int mt = 0; mt < 2; ++mt) {
      const int qrow = c * CC + mt * 16 + l16;   // row within batch; >=NPOS for pad rows
      bf16x8 a8[8];
      if (qrow < NPOS) {
        const float* xp = &xf[(b * NPOS + qrow) * DIM];
#pragma unroll
        for (int k = 0; k < 8; ++k) a8[k] = ld_cvt8(xp + k * 32 + quad * 8);
      } else {
#pragma unroll
        for (int k = 0; k < 8; ++k) a8[k] = bf16x8{0, 0, 0, 0, 0, 0, 0, 0};
      }
#pragma unroll
      for (int nt2 = 0; nt2 < 2; ++nt2) {
        const int wr = c * 768 + eh0 + nt2 * 16 + l16;
        floatx4 acc = fzero;
#pragma unroll
        for (int k = 0; k < 8; ++k) {
          const bf16x8 b8 = ld_cvt8(&w_in[wr * DIM + k * 32 + quad * 8]);
          acc = __builtin_amdgcn_mfma_f32_16x16x32_bf16(a8[k], b8, acc, 0, 0, 0);
        }
        const float bias = b_in[wr];
#pragma unroll
        for (int r = 0; r < 4; ++r)
          sQ[(mt * 16 + quad * 4 + r) * 264 + eh0 + nt2 * 16 + l16] =
              f2bf((acc[r] + bias) * scale);
      }
    }
  }

  // KV weight slab -> registers (converted once; compiler may re-stream from L2)
  const int wrow0 = c * 768 + 256 + w * 64;
  bf16x8 wreg[4][8];
#pragma unroll
  for (int m4 = 0; m4 < 4; ++m4)
#pragma unroll
    for (int k = 0; k < 8; ++k)
      wreg[m4][k] = ld_cvt8(&w_in[(wrow0 + m4 * 16 + l16) * DIM + k * 32 + quad * 8]);

  float ba[4][4];
#pragma unroll
  for (int m4 = 0; m4 < 4; ++m4) {
    const float4 bv = *(const float4*)&b_in[wrow0 + m4 * 16 + quad * 4];
    ba[m4][0] = bv.x; ba[m4][1] = bv.y; ba[m4][2] = bv.z; ba[m4][3] = bv.w;
  }

  floatx4 o_acc[2][2];   // un-normalized O
  floatx4 lacc[2];       // softmax denominators via ones-column MFMA
#pragma unroll
  for (int mt = 0; mt < 2; ++mt) {
#pragma unroll
    for (int nt2 = 0; nt2 < 2; ++nt2) o_acc[mt][nt2] = fzero;
    lacc[mt] = fzero;
  }
  const int eh = w * 32;

  __syncthreads();  // sQ + ones rows visible

  // hoist Q fragments; sQ region is then dead -> sP overlays it
  bf16x8 aqr[2];
#pragma unroll
  for (int mt = 0; mt < 2; ++mt)
    aqr[mt] = *(const bf16x8*)&sQ[(mt * 16 + l16) * 264 + eh + quad * 8];
  __syncthreads();  // all waves done reading sQ before anyone writes sP

  for (int t = 0; t < NTILES; ++t) {
    const int t0 = t * TKEY;

    // stage x tile [32][264] bf16 (inline f32->bf16; pad rows -> zero)
#pragma unroll
    for (int it = 0; it < 2; ++it) {
      const int cc2 = tid + it * 512;
      const int row = cc2 >> 5;
      const int col = (cc2 & 31) * 8;
      const int grow = t0 + row;
      bf16x8 v;
      if (grow < NPOS) {
        v = ld_cvt8(&xf[(b * NPOS + grow) * DIM + col]);
      } else {
        v = bf16x8{0, 0, 0, 0, 0, 0, 0, 0};
      }
      *(bf16x8*)&bufx[row * 264 + col] = v;
    }
    __syncthreads();  // barrier A: x tile staged (also fences prev tile's sK/sVT reads)

    // ---------------- KV^T projection
    {
      floatx4 acc[4][2];
#pragma unroll
      for (int m4 = 0; m4 < 4; ++m4)
#pragma unroll
        for (int n4 = 0; n4 < 2; ++n4) acc[m4][n4] = fzero;

#pragma unroll
      for (int k = 0; k < 8; ++k) {
        bf16x8 bfr[2];
#pragma unroll
        for (int n4 = 0; n4 < 2; ++n4)
          bfr[n4] = *(const bf16x8*)&bufx[(n4 * 16 + l16) * 264 + k * 32 + quad * 8];
#pragma unroll
        for (int m4 = 0; m4 < 4; ++m4)
#pragma unroll
          for (int n4 = 0; n4 < 2; ++n4)
            acc[m4][n4] = __builtin_amdgcn_mfma_f32_16x16x32_bf16(wreg[m4][k], bfr[n4],
                                                                  acc[m4][n4], 0, 0, 0);
      }
      // +bias, cvt bf16, store K [key][e] / V^T [e][key]
#pragma unroll
      for (int m4 = 0; m4 < 4; ++m4) {
#pragma unroll
        for (int n4 = 0; n4 < 2; ++n4) {
          const int key = n4 * 16 + l16;
          if (w < 4) {
            const int e0 = w * 64 + m4 * 16 + quad * 4;
            ushort4 pk;
            pk.x = f2bf(acc[m4][n4][0] + ba[m4][0]);
            pk.y = f2bf(acc[m4][n4][1] + ba[m4][1]);
            pk.z = f2bf(acc[m4][n4][2] + ba[m4][2]);
            pk.w = f2bf(acc[m4][n4][3] + ba[m4][3]);
            *(ushort4*)&sK[key * 264 + e0] = pk;
          } else {
            const int e0 = (w - 4) * 64 + m4 * 16 + quad * 4;
#pragma unroll
            for (int r = 0; r < 4; ++r)
              sVT[(e0 + r) * 40 + key] = f2bf(acc[m4][n4][r] + ba[m4][r]);
          }
        }
      }
    }
    __syncthreads();  // barrier B: K/V ready (also fences bufx reads vs next stage)

    // ---------------- scores + mask + exp (bounded inputs: no running max) + P
#pragma unroll
    for (int mt = 0; mt < 2; ++mt) {
#pragma unroll
      for (int n4 = 0; n4 < 2; ++n4) {
        const bf16x8 bk = *(const bf16x8*)&sK[(n4 * 16 + l16) * 264 + eh + quad * 8];
        const floatx4 sc = __builtin_amdgcn_mfma_f32_16x16x32_bf16(aqr[mt], bk, fzero, 0, 0, 0);
        const int kabs = t0 + n4 * 16 + l16;
        const unsigned ki = ((unsigned)kabs * 110377u) >> 21;  // kabs/19, kabs<=383
        const unsigned kj = (unsigned)kabs - ki * 19u;
#pragma unroll
        for (int r = 0; r < 4; ++r) {
          const unsigned j = (unsigned)(mt * 16 + quad * 4 + r);
          const bool ok = (kabs < NPOS) &&
                          (ki == (unsigned)c || kj == (unsigned)c || ki == j || kj == j);
          const float p = ok ? __expf(sc[r]) : 0.f;
          sP[(mt * 16 + quad * 4 + r) * 40 + n4 * 16 + l16] = f2bf(p);
        }
      }
    }

    // ---------------- PV: O += P @ [V | ones]  (sP wave-private, no barrier)
    {
      bf16x8 ap[2], bv8[2];
#pragma unroll
      for (int mt = 0; mt < 2; ++mt)
        ap[mt] = *(const bf16x8*)&sP[(mt * 16 + l16) * 40 + quad * 8];
#pragma unroll
      for (int nt2 = 0; nt2 < 2; ++nt2)
        bv8[nt2] = *(const bf16x8*)&sVT[(eh + nt2 * 16 + l16) * 40 + quad * 8];
      const bf16x8 bones = *(const bf16x8*)&sVT[(256 + l16) * 40 + quad * 8];
#pragma unroll
      for (int mt = 0; mt < 2; ++mt) {
#pragma unroll
        for (int nt2 = 0; nt2 < 2; ++nt2)
          o_acc[mt][nt2] =
              __builtin_amdgcn_mfma_f32_16x16x32_bf16(ap[mt], bv8[nt2], o_acc[mt][nt2], 0, 0, 0);
        lacc[mt] = __builtin_amdgcn_mfma_f32_16x16x32_bf16(ap[mt], bones, lacc[mt], 0, 0, 0);
      }
    }
  }  // tile loop

  // ---------------- finalize O -> bufx (attn-out bf16); l in lacc col 0
#pragma unroll
  for (int mt = 0; mt < 2; ++mt) {
    float invl[4];
#pragma unroll
    for (int r = 0; r < 4; ++r) {
      const float l = __shfl(lacc[mt][r], (lane & 48));  // col-0 lane of this quad-row
      invl[r] = 1.f / l;
    }
#pragma unroll
    for (int nt2 = 0; nt2 < 2; ++nt2)
#pragma unroll
      for (int r = 0; r < 4; ++r)
        bufx[(mt * 16 + quad * 4 + r) * 264 + eh + nt2 * 16 + l16] =
            f2bf(o_acc[mt][nt2][r] * invl[r]);
  }
  __syncthreads();

  // ---------------- GEMM1: proj = AO @ w_out^T + b_out -> sK (bf16)
#pragma unroll
  for (int mt = 0; mt < 2; ++mt) {
    bf16x8 a8[8];
#pragma unroll
    for (int k = 0; k < 8; ++k)
      a8[k] = *(const bf16x8*)&bufx[(mt * 16 + l16) * 264 + k * 32 + quad * 8];
#pragma unroll
    for (int nt2 = 0; nt2 < 2; ++nt2) {
      const int e0 = w * 32 + nt2 * 16;
      floatx4 acc = fzero;
#pragma unroll
      for (int k = 0; k < 8; ++k) {
        const bf16x8 b8 = ld_cvt8(&w_out[(c * 256 + e0 + l16) * DIM + k * 32 + quad * 8]);
        acc = __builtin_amdgcn_mfma_f32_16x16x32_bf16(a8[k], b8, acc, 0, 0, 0);
      }
      const float bias = b_out[c * 256 + e0 + l16];
#pragma unroll
      for (int r = 0; r < 4; ++r)
        sK[(mt * 16 + quad * 4 + r) * 264 + e0 + l16] = f2bf(acc[r] + bias);
    }
  }
  __syncthreads();

  // ---------------- GEMM2: out = proj @ w_fuse^T + b_fuse + x
#pragma unroll
  for (int mt = 0; mt < 2; ++mt) {
    bf16x8 a8[8];
#pragma unroll
    for (int k = 0; k < 8; ++k)
      a8[k] = *(const bf16x8*)&sK[(mt * 16 + l16) * 264 + k * 32 + quad * 8];
#pragma unroll
    for (int nt2 = 0; nt2 < 2; ++nt2) {
      const int e0 = w * 32 + nt2 * 16;
      floatx4 acc = fzero;
#pragma unroll
      for (int k = 0; k < 8; ++k) {
        const bf16x8 b8 = ld_cvt8(&w_fuse[(e0 + l16) * DIM + k * 32 + quad * 8]);
        acc = __builtin_amdgcn_mfma_f32_16x16x32_bf16(a8[k], b8, acc, 0, 0, 0);
      }
      const float bfu = b_fuse[e0 + l16];
#pragma unroll
      for (int r = 0; r < 4; ++r) {
        const int row = mt * 16 + quad * 4 + r;
        if (row < CC) {
          const int gp = (b * NPOS + c * CC + row) * DIM + e0 + l16;
          out[gp] = acc[r] + bfu + xf[gp];
        }
      }
    }
  }
}

extern "C" void kernel_launch(void* const* d_in, const int* in_sizes, int n_in,
                              void* d_out, int out_size, void* d_ws, size_t ws_size,
                              hipStream_t stream) {
  const float* x      = (const float*)d_in[0];
  const float* w_in   = (const float*)d_in[1];
  const float* b_in   = (const float*)d_in[2];
  const float* w_out  = (const float*)d_in[3];
  const float* b_out  = (const float*)d_in[4];
  const float* w_fuse = (const float*)d_in[5];
  const float* b_fuse = (const float*)d_in[6];
  float* out = (float*)d_out;

  (void)d_ws; (void)ws_size;  // all conversion is inline now — single dispatch

  (void)hipFuncSetAttribute((const void*)cgca_kernel,
                            hipFuncAttributeMaxDynamicSharedMemorySize, LDS_BYTES);
  cgca_kernel<<<608, 512, LDS_BYTES, stream>>>(x, w_in, b_in, w_out, b_out, w_fuse,
                                               b_fuse, out);
}

// Round 9
// 334.311 us; speedup vs baseline: 1.5282x; 1.5282x over previous
//
#include <hip/hip_runtime.h>

#define CC 19
#define NPOS 361
#define NPAD 384
#define DIM 256
#define TKEY 32
#define NTILES 12

using bf16x8 = __attribute__((ext_vector_type(8))) short;
using floatx4 = __attribute__((ext_vector_type(4))) float;

__device__ __forceinline__ unsigned short f2bf(float f) {
  unsigned u = __builtin_bit_cast(unsigned, f);
  u += 0x7fffu + ((u >> 16) & 1u);
  return (unsigned short)(u >> 16);
}

// fused conversion: x (zero-padded 361->384 rows) + all weights, f32 -> bf16
__global__ void conv_all_kernel(const float* __restrict__ x,
                                const float* __restrict__ w_in,
                                const float* __restrict__ w_out,
                                const float* __restrict__ w_fuse,
                                unsigned short* __restrict__ ws) {
  const int j = blockIdx.x * 256 + threadIdx.x;
  float4 v = make_float4(0.f, 0.f, 0.f, 0.f);
  unsigned short* dst;
  if (j < 786432) {
    const int row = j >> 6;
    const int off = (j & 63) << 2;
    const int b = row / NPAD;
    const int r = row - b * NPAD;
    if (r < NPOS) v = *(const float4*)&x[(b * NPOS + r) * DIM + off];
    dst = &ws[row * DIM + off];
  } else if (j < 1720320) {
    const int k = j - 786432;
    v = *(const float4*)&w_in[k << 2];
    dst = &ws[3145728 + (k << 2)];
  } else if (j < 2031616) {
    const int k = j - 1720320;
    v = *(const float4*)&w_out[k << 2];
    dst = &ws[6881280 + (k << 2)];
  } else {
    const int k = j - 2031616;
    v = *(const float4*)&w_fuse[k << 2];
    dst = &ws[8126464 + (k << 2)];
  }
  ushort4 o;
  o.x = f2bf(v.x); o.y = f2bf(v.y); o.z = f2bf(v.z); o.w = f2bf(v.w);
  *(ushort4*)dst = o;
}

// Attention: one block per (c, b, head-group g). 4 waves = 4 heads.
// launch_bounds (256,2): min 2 blocks/CU -> reg cap 256 (natural liveset
// ~230 unified incl. wreg/accs -> NO spills; R2/R4/R8: capping below liveset
// spills at 3x cost). 2 co-resident 4-wave blocks/CU = cross-block overlap
// that the 8-wave single-block structure could never get.
// LDS static 56KB -> 2 blocks fit (112KB of 160KB).
__launch_bounds__(256, 2)
__global__ void attn_kernel(const float* __restrict__ b_in,
                            const unsigned short* __restrict__ xbf,
                            const unsigned short* __restrict__ wibf,
                            float* __restrict__ out) {
  // XCD swizzle: same channel -> same XCD (1216 = 8 * 152 blocks)
  const int bid = blockIdx.x;
  const int xcd = bid & 7;
  const int slot = bid >> 3;
  int c, b, g;
  if (slot < 128) {
    c = ((slot >> 6) << 3) + xcd;       // channels 0..15
    const int r = slot & 63;
    b = r & 31; g = r >> 5;
  } else {
    const int widx = ((slot - 128) << 3) + xcd;  // 0..191
    c = 16 + (widx >> 6);               // channels 16..18
    const int r = widx & 63;
    b = r & 31; g = r >> 5;
  }

  const int tid = threadIdx.x;
  const int w = tid >> 6;        // wave 0..3; head = g*4 + w
  const int lane = tid & 63;
  const int quad = lane >> 4;
  const int l16 = lane & 15;
  const int el = w * 32;         // head's e-offset within the 128-col group

  __shared__ unsigned short sQ[32 * 136];    // wave-private cols -> no barriers
  __shared__ unsigned short sK[32 * 136];
  __shared__ unsigned short sVT[144 * 40];   // rows 128..143: ones/zeros
  __shared__ unsigned short sX[32 * 264];
  __shared__ unsigned short sPall[4 * 32 * 40];
  unsigned short* sP = sPall + w * 1280;     // wave-private

  const float scale = 0.17677669529663687f;  // 1/sqrt(32)
  const floatx4 fzero = {0.f, 0.f, 0.f, 0.f};

  // ones-column rows for the softmax-denominator MFMA (row 128 = 1.0, rest 0)
  for (int i = tid; i < 16 * 40; i += 256) {
    const int row = i / 40;
    const int col = i - row * 40;
    sVT[(128 + row) * 40 + col] = (row == 0) ? (unsigned short)0x3F80 : (unsigned short)0;
  }

  // ---------------- Q = xq @ wq^T + bq (scaled) -> sQ cols [el, el+32) (wave-private)
  {
#pragma unroll
    for (int mt = 0; mt < 2; ++mt) {
      const int xrow = b * NPAD + c * CC + mt * 16 + l16;  // zero-padded rows
      bf16x8 a8[8];
#pragma unroll
      for (int k = 0; k < 8; ++k)
        a8[k] = *(const bf16x8*)&xbf[xrow * DIM + k * 32 + quad * 8];
#pragma unroll
      for (int nt2 = 0; nt2 < 2; ++nt2) {
        const int wr = c * 768 + g * 128 + el + nt2 * 16 + l16;
        floatx4 acc = fzero;
#pragma unroll
        for (int k = 0; k < 8; ++k) {
          bf16x8 b8 = *(const bf16x8*)&wibf[wr * DIM + k * 32 + quad * 8];
          acc = __builtin_amdgcn_mfma_f32_16x16x32_bf16(a8[k], b8, acc, 0, 0, 0);
        }
        const float bias = b_in[wr];
#pragma unroll
        for (int r = 0; r < 4; ++r)
          sQ[(mt * 16 + quad * 4 + r) * 136 + el + nt2 * 16 + l16] =
              f2bf((acc[r] + bias) * scale);
      }
    }
  }

  // KV weight slab -> registers once: waves 0,1 = K-slice rows, 2,3 = V-slice
  const int wrow0 = (w < 2) ? (c * 768 + 256 + g * 128 + w * 64)
                            : (c * 768 + 512 + g * 128 + (w - 2) * 64);
  bf16x8 wreg[4][8];
#pragma unroll
  for (int m4 = 0; m4 < 4; ++m4)
#pragma unroll
    for (int k = 0; k < 8; ++k)
      wreg[m4][k] = *(const bf16x8*)&wibf[(wrow0 + m4 * 16 + l16) * DIM + k * 32 + quad * 8];

  float ba[4][4];
#pragma unroll
  for (int m4 = 0; m4 < 4; ++m4) {
    const float4 bv = *(const float4*)&b_in[wrow0 + m4 * 16 + quad * 4];
    ba[m4][0] = bv.x; ba[m4][1] = bv.y; ba[m4][2] = bv.z; ba[m4][3] = bv.w;
  }

  // hoist Q A-fragments (same-wave LDS round-trip; lgkmcnt orders it)
  bf16x8 aqr[2];
#pragma unroll
  for (int mt = 0; mt < 2; ++mt)
    aqr[mt] = *(const bf16x8*)&sQ[(mt * 16 + l16) * 136 + el + quad * 8];

  floatx4 o_acc[2][2];   // un-normalized O
  floatx4 lacc[2];       // softmax denominators via ones-column MFMA
#pragma unroll
  for (int mt = 0; mt < 2; ++mt) {
#pragma unroll
    for (int nt2 = 0; nt2 < 2; ++nt2) o_acc[mt][nt2] = fzero;
    lacc[mt] = fzero;
  }

  for (int t = 0; t < NTILES; ++t) {
    const int t0 = t * TKEY;

    // stage x tile [32][264] bf16 (prev proj reads of sX done: before barrier B(t-1))
#pragma unroll
    for (int it = 0; it < 4; ++it) {
      const int cc2 = tid + it * 256;
      const int row = cc2 >> 5;
      const int col = (cc2 & 31) * 8;
      *(bf16x8*)&sX[row * 264 + col] = *(const bf16x8*)&xbf[(b * NPAD + t0 + row) * DIM + col];
    }
    __syncthreads();  // barrier A: x staged; also fences scores/PV(t-1) reads of sK/sVT

    // ---------------- K/V slice projection from register-resident weights
    {
      floatx4 acc[4][2];
#pragma unroll
      for (int m4 = 0; m4 < 4; ++m4)
#pragma unroll
        for (int n4 = 0; n4 < 2; ++n4) acc[m4][n4] = fzero;

#pragma unroll
      for (int k = 0; k < 8; ++k) {
        bf16x8 bfr[2];
#pragma unroll
        for (int n4 = 0; n4 < 2; ++n4)
          bfr[n4] = *(const bf16x8*)&sX[(n4 * 16 + l16) * 264 + k * 32 + quad * 8];
#pragma unroll
        for (int m4 = 0; m4 < 4; ++m4)
#pragma unroll
          for (int n4 = 0; n4 < 2; ++n4)
            acc[m4][n4] = __builtin_amdgcn_mfma_f32_16x16x32_bf16(wreg[m4][k], bfr[n4],
                                                                  acc[m4][n4], 0, 0, 0);
      }
#pragma unroll
      for (int m4 = 0; m4 < 4; ++m4) {
#pragma unroll
        for (int n4 = 0; n4 < 2; ++n4) {
          const int key = n4 * 16 + l16;
          if (w < 2) {
            const int e0 = w * 64 + m4 * 16 + quad * 4;
            ushort4 pk;
            pk.x = f2bf(acc[m4][n4][0] + ba[m4][0]);
            pk.y = f2bf(acc[m4][n4][1] + ba[m4][1]);
            pk.z = f2bf(acc[m4][n4][2] + ba[m4][2]);
            pk.w = f2bf(acc[m4][n4][3] + ba[m4][3]);
            *(ushort4*)&sK[key * 136 + e0] = pk;
          } else {
            const int e0 = (w - 2) * 64 + m4 * 16 + quad * 4;
#pragma unroll
            for (int r = 0; r < 4; ++r)
              sVT[(e0 + r) * 40 + key] = f2bf(acc[m4][n4][r] + ba[m4][r]);
          }
        }
      }
    }
    __syncthreads();  // barrier B: K/V ready

    // ---------------- scores + mask + exp (bounded inputs: no running max) + P
#pragma unroll
    for (int mt = 0; mt < 2; ++mt) {
#pragma unroll
      for (int n4 = 0; n4 < 2; ++n4) {
        const bf16x8 bk = *(const bf16x8*)&sK[(n4 * 16 + l16) * 136 + el + quad * 8];
        const floatx4 sc = __builtin_amdgcn_mfma_f32_16x16x32_bf16(aqr[mt], bk, fzero, 0, 0, 0);
        const int kabs = t0 + n4 * 16 + l16;
        const unsigned ki = ((unsigned)kabs * 110377u) >> 21;  // kabs/19, kabs<=383
        const unsigned kj = (unsigned)kabs - ki * 19u;
#pragma unroll
        for (int r = 0; r < 4; ++r) {
          const unsigned j = (unsigned)(mt * 16 + quad * 4 + r);
          const bool ok = (kabs < NPOS) &&
                          (ki == (unsigned)c || kj == (unsigned)c || ki == j || kj == j);
          const float p = ok ? __expf(sc[r]) : 0.f;
          sP[(mt * 16 + quad * 4 + r) * 40 + n4 * 16 + l16] = f2bf(p);
        }
      }
    }

    // ---------------- PV: O += P @ [V | ones]  (sP wave-private, no barrier)
    {
      bf16x8 ap[2], bv8[2];
#pragma unroll
      for (int mt = 0; mt < 2; ++mt)
        ap[mt] = *(const bf16x8*)&sP[(mt * 16 + l16) * 40 + quad * 8];
#pragma unroll
      for (int nt2 = 0; nt2 < 2; ++nt2)
        bv8[nt2] = *(const bf16x8*)&sVT[(el + nt2 * 16 + l16) * 40 + quad * 8];
      const bf16x8 bones = *(const bf16x8*)&sVT[(128 + l16) * 40 + quad * 8];
#pragma unroll
      for (int mt = 0; mt < 2; ++mt) {
#pragma unroll
        for (int nt2 = 0; nt2 < 2; ++nt2)
          o_acc[mt][nt2] =
              __builtin_amdgcn_mfma_f32_16x16x32_bf16(ap[mt], bv8[nt2], o_acc[mt][nt2], 0, 0, 0);
        lacc[mt] = __builtin_amdgcn_mfma_f32_16x16x32_bf16(ap[mt], bones, lacc[mt], 0, 0, 0);
      }
    }
  }  // tile loop

  // ---------------- AO = O/l (f32) -> d_out staging, rows j<19 only
#pragma unroll
  for (int mt = 0; mt < 2; ++mt) {
    float invl[4];
#pragma unroll
    for (int r = 0; r < 4; ++r) {
      const float l = __shfl(lacc[mt][r], (lane & 48));  // col-0 lane of this quad-row
      invl[r] = 1.f / l;
    }
#pragma unroll
    for (int nt2 = 0; nt2 < 2; ++nt2) {
#pragma unroll
      for (int r = 0; r < 4; ++r) {
        const int j = mt * 16 + quad * 4 + r;
        if (j < CC) {
          out[(b * NPOS + c * CC + j) * DIM + g * 128 + el + nt2 * 16 + l16] =
              o_acc[mt][nt2][r] * invl[r];
        }
      }
    }
  }
}

// Epilogue: per (c,b): proj = AO @ w_out^T + b_out; out = proj @ w_fuse^T + b_fuse + x.
// Reads AO (f32) from d_out rows c*19..c*19+18, then overwrites those rows.
__launch_bounds__(256, 2)
__global__ void epi_kernel(const float* __restrict__ xf,
                           const float* __restrict__ b_out,
                           const float* __restrict__ b_fuse,
                           const unsigned short* __restrict__ wobf,
                           const unsigned short* __restrict__ wfbf,
                           float* __restrict__ out) {
  const int bid = blockIdx.x;
  const int xcd = bid & 7;
  const int slot = bid >> 3;
  int c, b;
  if (slot < 64) {
    c = ((slot >> 5) << 3) + xcd;
    b = slot & 31;
  } else {
    const int widx = ((slot - 64) << 3) + xcd;
    c = 16 + (widx >> 5);
    b = widx & 31;
  }

  const int tid = threadIdx.x;
  const int w = tid >> 6;
  const int lane = tid & 63;
  const int quad = lane >> 4;
  const int l16 = lane & 15;

  __shared__ unsigned short sAO[32 * 264];
  __shared__ unsigned short sT[32 * 264];
  const floatx4 fzero = {0.f, 0.f, 0.f, 0.f};

  // load AO f32 -> bf16 LDS, zero rows >= 19
#pragma unroll
  for (int it = 0; it < 8; ++it) {
    const int cc2 = tid + it * 256;
    const int row = cc2 >> 6;
    const int col = (cc2 & 63) * 4;
    float4 v = make_float4(0.f, 0.f, 0.f, 0.f);
    if (row < CC) v = *(const float4*)&out[(b * NPOS + c * CC + row) * DIM + col];
    ushort4 o;
    o.x = f2bf(v.x); o.y = f2bf(v.y); o.z = f2bf(v.z); o.w = f2bf(v.w);
    *(ushort4*)&sAO[row * 264 + col] = o;
  }
  __syncthreads();

  // GEMM1: proj = AO @ w_out^T + b_out -> sT
#pragma unroll
  for (int mt = 0; mt < 2; ++mt) {
    bf16x8 a8[8];
#pragma unroll
    for (int k = 0; k < 8; ++k)
      a8[k] = *(const bf16x8*)&sAO[(mt * 16 + l16) * 264 + k * 32 + quad * 8];
#pragma unroll
    for (int nt = 0; nt < 4; ++nt) {
      const int e0 = w * 64 + nt * 16;
      floatx4 acc = fzero;
#pragma unroll
      for (int k = 0; k < 8; ++k) {
        bf16x8 b8 = *(const bf16x8*)&wobf[(c * 256 + e0 + l16) * DIM + k * 32 + quad * 8];
        acc = __builtin_amdgcn_mfma_f32_16x16x32_bf16(a8[k], b8, acc, 0, 0, 0);
      }
      const float bias = b_out[c * 256 + e0 + l16];
#pragma unroll
      for (int r = 0; r < 4; ++r)
        sT[(mt * 16 + quad * 4 + r) * 264 + e0 + l16] = f2bf(acc[r] + bias);
    }
  }
  __syncthreads();

  // GEMM2: out = proj @ w_fuse^T + b_fuse + x
#pragma unroll
  for (int mt = 0; mt < 2; ++mt) {
    bf16x8 a8[8];
#pragma unroll
    for (int k = 0; k < 8; ++k)
      a8[k] = *(const bf16x8*)&sT[(mt * 16 + l16) * 264 + k * 32 + quad * 8];
#pragma unroll
    for (int nt = 0; nt < 4; ++nt) {
      const int e0 = w * 64 + nt * 16;
      floatx4 acc = fzero;
#pragma unroll
      for (int k = 0; k < 8; ++k) {
        bf16x8 b8 = *(const bf16x8*)&wfbf[(e0 + l16) * DIM + k * 32 + quad * 8];
        acc = __builtin_amdgcn_mfma_f32_16x16x32_bf16(a8[k], b8, acc, 0, 0, 0);
      }
      const float bfu = b_fuse[e0 + l16];
#pragma unroll
      for (int r = 0; r < 4; ++r) {
        const int row = mt * 16 + quad * 4 + r;
        if (row < CC) {
          const int gp = (b * NPOS + c * CC + row) * DIM + e0 + l16;
          out[gp] = acc[r] + bfu + xf[gp];
        }
      }
    }
  }
}

extern "C" void kernel_launch(void* const* d_in, const int* in_sizes, int n_in,
                              void* d_out, int out_size, void* d_ws, size_t ws_size,
                              hipStream_t stream) {
  const float* x      = (const float*)d_in[0];
  const float* w_in   = (const float*)d_in[1];
  const float* b_in   = (const float*)d_in[2];
  const float* w_out  = (const float*)d_in[3];
  const float* b_out  = (const float*)d_in[4];
  const float* w_fuse = (const float*)d_in[5];
  const float* b_fuse = (const float*)d_in[6];
  float* out = (float*)d_out;

  if (ws_size < (size_t)16384000) return;  // 16.38 MB bf16 scratch (validated bound)

  unsigned short* ws = (unsigned short*)d_ws;
  unsigned short* x_bf  = ws;              // 32*384*256   = 3,145,728
  unsigned short* wi_bf = ws + 3145728;    // 19*768*256   = 3,735,552
  unsigned short* wo_bf = ws + 6881280;    // 19*256*256   = 1,245,184
  unsigned short* wf_bf = ws + 8126464;    // 256*256      = 65,536

  conv_all_kernel<<<8000, 256, 0, stream>>>(x, w_in, w_out, w_fuse, ws);
  attn_kernel<<<1216, 256, 0, stream>>>(b_in, x_bf, wi_bf, out);
  epi_kernel<<<608, 256, 0, stream>>>(x, b_out, b_fuse, wo_bf, wf_bf, out);
}

// Round 10
// 285.065 us; speedup vs baseline: 1.7921x; 1.1728x over previous
//
#include <hip/hip_runtime.h>

#define CC 19
#define NPOS 361
#define NPAD 384
#define DIM 256
#define TKEY 32
#define NTILES 12

// LDS layout (bytes), double-buffered pipeline, 1 barrier/tile, NO sP:
//   sQ     : 32 x 264 bf16              = 16896   [0)
//   bufx   : 2 x 32 x 264 bf16          = 33792   [16896)
//   sK     : 2 x 32 x 264 bf16          = 33792   [50688)
//   sVT    : 2 x 272 x 40 f16           = 43520   [84480)  rows 256..271 ones/zeros
// total = 128000 (1 block/CU is structural at this unified-reg liveset)
#define LDS_BYTES 128000

using bf16x8 = __attribute__((ext_vector_type(8))) short;
using f16x4  = __attribute__((ext_vector_type(4))) _Float16;
using floatx4 = __attribute__((ext_vector_type(4))) float;
using uintx2 = __attribute__((ext_vector_type(2))) unsigned int;

__device__ __forceinline__ unsigned short f2bf(float f) {
  unsigned u = __builtin_bit_cast(unsigned, f);
  u += 0x7fffu + ((u >> 16) & 1u);
  return (unsigned short)(u >> 16);
}

__device__ __forceinline__ unsigned short f2h(float f) {
  // single f32 -> f16 bits via v_cvt_pkrtz (low half)
  auto h = __builtin_amdgcn_cvt_pkrtz(f, 0.f);
  return (unsigned short)(__builtin_bit_cast(unsigned, h) & 0xffffu);
}

// fused conversion: x (zero-padded 361->384 rows) + all weights, f32 -> bf16
__global__ void conv_all_kernel(const float* __restrict__ x,
                                const float* __restrict__ w_in,
                                const float* __restrict__ w_out,
                                const float* __restrict__ w_fuse,
                                unsigned short* __restrict__ ws) {
  const int j = blockIdx.x * 256 + threadIdx.x;
  float4 v = make_float4(0.f, 0.f, 0.f, 0.f);
  unsigned short* dst;
  if (j < 786432) {
    const int row = j >> 6;
    const int off = (j & 63) << 2;
    const int b = row / NPAD;
    const int r = row - b * NPAD;
    if (r < NPOS) v = *(const float4*)&x[(b * NPOS + r) * DIM + off];
    dst = &ws[row * DIM + off];
  } else if (j < 1720320) {
    const int k = j - 786432;
    v = *(const float4*)&w_in[k << 2];
    dst = &ws[3145728 + (k << 2)];
  } else if (j < 2031616) {
    const int k = j - 1720320;
    v = *(const float4*)&w_out[k << 2];
    dst = &ws[6881280 + (k << 2)];
  } else {
    const int k = j - 2031616;
    v = *(const float4*)&w_fuse[k << 2];
    dst = &ws[8126464 + (k << 2)];
  }
  ushort4 o;
  o.x = f2bf(v.x); o.y = f2bf(v.y); o.z = f2bf(v.z); o.w = f2bf(v.w);
  *(ushort4*)dst = o;
}

// launch_bounds (512,2): VGPR cap 256 -> no spills (R2/R4/R8: capping below the
// natural ~230-reg unified liveset spills at 3x cost; occupancy is pinned at
// 2 waves/SIMD regardless -> minimize per-block latency instead).
__launch_bounds__(512, 2)
__global__ void cgca_kernel(const float* __restrict__ xf,
                            const float* __restrict__ b_in,
                            const float* __restrict__ b_out,
                            const float* __restrict__ b_fuse,
                            const unsigned short* __restrict__ xbf,
                            const unsigned short* __restrict__ wibf,
                            const unsigned short* __restrict__ wobf,
                            const unsigned short* __restrict__ wfbf,
                            float* __restrict__ out) {
  // XCD-aware swizzle: same channel's 32 batches contiguous on one XCD.
  const int bid = blockIdx.x;
  const int xcd = bid & 7;
  const int slot = bid >> 3;
  int c, b;
  if (slot < 64) {
    c = ((slot >> 5) << 3) + xcd;   // channels 0..15
    b = slot & 31;
  } else {
    const int widx = ((slot - 64) << 3) + xcd;  // 0..95
    c = 16 + (widx >> 5);           // channels 16..18
    b = widx & 31;
  }

  const int tid = threadIdx.x;
  const int w = tid >> 6;        // wave 0..7 == head index
  const int lane = tid & 63;
  const int quad = lane >> 4;
  const int l16 = lane & 15;

  extern __shared__ char smem[];
  unsigned short* sQ    = (unsigned short*)(smem);
  unsigned short* bufx0 = (unsigned short*)(smem + 16896);
  unsigned short* bufx1 = (unsigned short*)(smem + 16896 + 16896);
  unsigned short* sK0   = (unsigned short*)(smem + 50688);
  unsigned short* sK1   = (unsigned short*)(smem + 50688 + 16896);
  unsigned short* sVT0  = (unsigned short*)(smem + 84480);   // f16 payload
  unsigned short* sVT1  = (unsigned short*)(smem + 84480 + 21760);

  const float scale = 0.17677669529663687f;  // 1/sqrt(32)
  const floatx4 fzero = {0.f, 0.f, 0.f, 0.f};

  // ones/zero rows 256..271 of both sVT buffers (ones-column for the softmax
  // denominator). f16 1.0 = 0x3C00 at row 256; rest 0.
  for (int i = tid; i < 2 * 16 * 40; i += 512) {
    const int buf = i >= 640;
    const int idx = buf ? (i - 640) : i;
    const int row = idx / 40;
    const int col = idx - row * 40;
    unsigned short val = (row == 0) ? (unsigned short)0x3C00 : (unsigned short)0;
    (buf ? sVT1 : sVT0)[(256 + row) * 40 + col] = val;
  }

  // ---------------- Phase 1: Q = xq @ wq^T + bq (scaled) -> sQ bf16 [32][264]
  {
    const int eh0 = w * 32;
#pragma unroll
    for (int mt = 0; mt < 2; ++mt) {
      const int xrow = b * NPAD + c * CC + mt * 16 + l16;  // zero-padded rows
      bf16x8 a8[8];
#pragma unroll
      for (int k = 0; k < 8; ++k)
        a8[k] = *(const bf16x8*)&xbf[xrow * DIM + k * 32 + quad * 8];
#pragma unroll
      for (int nt2 = 0; nt2 < 2; ++nt2) {
        const int e0 = eh0 + nt2 * 16;
        floatx4 acc = fzero;
#pragma unroll
        for (int k = 0; k < 8; ++k) {
          bf16x8 b8 = *(const bf16x8*)&wibf[(c * 768 + e0 + l16) * DIM + k * 32 + quad * 8];
          acc = __builtin_amdgcn_mfma_f32_16x16x32_bf16(a8[k], b8, acc, 0, 0, 0);
        }
        const float bias = b_in[c * 768 + e0 + l16];
#pragma unroll
        for (int r = 0; r < 4; ++r)
          sQ[(mt * 16 + quad * 4 + r) * 264 + e0 + l16] = f2bf((acc[r] + bias) * scale);
      }
    }
  }

  // KV weight slab -> registers once (loop-invariant across 12 tiles)
  const int wrow0 = c * 768 + 256 + w * 64;
  bf16x8 wreg[4][8];
#pragma unroll
  for (int m4 = 0; m4 < 4; ++m4)
#pragma unroll
    for (int k = 0; k < 8; ++k)
      wreg[m4][k] = *(const bf16x8*)&wibf[(wrow0 + m4 * 16 + l16) * DIM + k * 32 + quad * 8];

  float ba[4][4];
#pragma unroll
  for (int m4 = 0; m4 < 4; ++m4) {
    const float4 bv = *(const float4*)&b_in[wrow0 + m4 * 16 + quad * 4];
    ba[m4][0] = bv.x; ba[m4][1] = bv.y; ba[m4][2] = bv.z; ba[m4][3] = bv.w;
  }

  // stage x tile 0 -> bufx0
#pragma unroll
  for (int it = 0; it < 2; ++it) {
    const int cc2 = tid + it * 512;
    const int row = cc2 >> 5;
    const int col = (cc2 & 31) * 8;
    *(bf16x8*)&bufx0[row * 264 + col] = *(const bf16x8*)&xbf[(b * NPAD + row) * DIM + col];
  }

  floatx4 o_acc[2][2];   // un-normalized O
  floatx4 lacc[2];       // softmax denominators via ones-column MFMA
#pragma unroll
  for (int mt = 0; mt < 2; ++mt) {
#pragma unroll
    for (int nt2 = 0; nt2 < 2; ++nt2) o_acc[mt][nt2] = fzero;
    lacc[mt] = fzero;
  }
  const int eh = w * 32;

  __syncthreads();  // Q in sQ, x(0) staged, ones rows written

  // hoist Q B-fragments (wave-own sQ rows/cols; lgkmcnt orders the round-trip)
  bf16x8 aqr[2];
#pragma unroll
  for (int mt = 0; mt < 2; ++mt)
    aqr[mt] = *(const bf16x8*)&sQ[(mt * 16 + l16) * 264 + eh + quad * 8];

  for (int t = 0; t < NTILES; ++t) {
    const int t0 = t * TKEY;
    unsigned short* bx  = (t & 1) ? bufx1 : bufx0;
    unsigned short* bxn = (t & 1) ? bufx0 : bufx1;
    unsigned short* sK  = (t & 1) ? sK1 : sK0;
    unsigned short* sVT = (t & 1) ? sVT1 : sVT0;

    // stage x(t+1) -> other buffer
    if (t + 1 < NTILES) {
#pragma unroll
      for (int it = 0; it < 2; ++it) {
        const int cc2 = tid + it * 512;
        const int row = cc2 >> 5;
        const int col = (cc2 & 31) * 8;
        *(bf16x8*)&bxn[row * 264 + col] =
            *(const bf16x8*)&xbf[(b * NPAD + t0 + TKEY + row) * DIM + col];
      }
    }

    // ---------------- KV^T projection from register-resident weights
    {
      floatx4 acc[4][2];
#pragma unroll
      for (int m4 = 0; m4 < 4; ++m4)
#pragma unroll
        for (int n4 = 0; n4 < 2; ++n4) acc[m4][n4] = fzero;

#pragma unroll
      for (int k = 0; k < 8; ++k) {
        bf16x8 bfr[2];
#pragma unroll
        for (int n4 = 0; n4 < 2; ++n4)
          bfr[n4] = *(const bf16x8*)&bx[(n4 * 16 + l16) * 264 + k * 32 + quad * 8];
#pragma unroll
        for (int m4 = 0; m4 < 4; ++m4)
#pragma unroll
          for (int n4 = 0; n4 < 2; ++n4)
            acc[m4][n4] = __builtin_amdgcn_mfma_f32_16x16x32_bf16(wreg[m4][k], bfr[n4],
                                                                  acc[m4][n4], 0, 0, 0);
      }
      // +bias; K -> bf16 [key][e] (vector stores); V^T -> f16 [e][key]
#pragma unroll
      for (int m4 = 0; m4 < 4; ++m4) {
#pragma unroll
        for (int n4 = 0; n4 < 2; ++n4) {
          const int key = n4 * 16 + l16;
          if (w < 4) {
            const int e0 = w * 64 + m4 * 16 + quad * 4;
            ushort4 pk;
            pk.x = f2bf(acc[m4][n4][0] + ba[m4][0]);
            pk.y = f2bf(acc[m4][n4][1] + ba[m4][1]);
            pk.z = f2bf(acc[m4][n4][2] + ba[m4][2]);
            pk.w = f2bf(acc[m4][n4][3] + ba[m4][3]);
            *(ushort4*)&sK[key * 264 + e0] = pk;
          } else {
            const int e0 = (w - 4) * 64 + m4 * 16 + quad * 4;
#pragma unroll
            for (int r = 0; r < 4; ++r)
              sVT[(e0 + r) * 40 + key] = f2h(acc[m4][n4][r] + ba[m4][r]);
          }
        }
      }
    }
    __syncthreads();  // the ONE barrier: kv[t] ready

    // ---------------- scores (TRANSPOSED) + mask + exp + register-P + PV
    // scT = MFMA(bk, aq): D[m=key][n=q] -> col=l16=q, row=quad*4+r=key.
    // Lane then holds P[q=l16][key=quad*4+j] == the A-fragment of the K=16
    // f16 MFMA -> P never round-trips through LDS.
#pragma unroll
    for (int mt = 0; mt < 2; ++mt) {
      f16x4 ap[2];
#pragma unroll
      for (int n4 = 0; n4 < 2; ++n4) {
        const bf16x8 bk = *(const bf16x8*)&sK[(n4 * 16 + l16) * 264 + eh + quad * 8];
        const floatx4 scT = __builtin_amdgcn_mfma_f32_16x16x32_bf16(bk, aqr[mt], fzero, 0, 0, 0);
        const int kbase = t0 + n4 * 16 + quad * 4;
        const unsigned q = (unsigned)(mt * 16 + l16);
        float p[4];
#pragma unroll
        for (int r = 0; r < 4; ++r) {
          const int kabs = kbase + r;
          const unsigned ki = ((unsigned)kabs * 110377u) >> 21;  // kabs/19, kabs<=383
          const unsigned kj = (unsigned)kabs - ki * 19u;
          const bool ok = (kabs < NPOS) &&
                          (ki == (unsigned)c || kj == (unsigned)c || ki == q || kj == q);
          p[r] = ok ? __expf(scT[r]) : 0.f;
        }
        const auto h01 = __builtin_amdgcn_cvt_pkrtz(p[0], p[1]);
        const auto h23 = __builtin_amdgcn_cvt_pkrtz(p[2], p[3]);
        uintx2 uv = {__builtin_bit_cast(unsigned, h01), __builtin_bit_cast(unsigned, h23)};
        ap[n4] = __builtin_bit_cast(f16x4, uv);
      }
      // PV: O += P @ [V | ones], two K=16 steps (f16)
#pragma unroll
      for (int n4 = 0; n4 < 2; ++n4) {
#pragma unroll
        for (int nt2 = 0; nt2 < 2; ++nt2) {
          const f16x4 bv =
              *(const f16x4*)&sVT[(eh + nt2 * 16 + l16) * 40 + n4 * 16 + quad * 4];
          o_acc[mt][nt2] =
              __builtin_amdgcn_mfma_f32_16x16x16f16(ap[n4], bv, o_acc[mt][nt2], 0, 0, 0);
        }
        const f16x4 bo = *(const f16x4*)&sVT[(256 + l16) * 40 + n4 * 16 + quad * 4];
        lacc[mt] = __builtin_amdgcn_mfma_f32_16x16x16f16(ap[n4], bo, lacc[mt], 0, 0, 0);
      }
    }
  }  // tile loop

  // ---------------- finalize O -> bufx0 (attn-out bf16); l in lacc col 0
#pragma unroll
  for (int mt = 0; mt < 2; ++mt) {
    float invl[4];
#pragma unroll
    for (int r = 0; r < 4; ++r) {
      const float l = __shfl(lacc[mt][r], (lane & 48));  // col-0 lane of this quad-row
      invl[r] = 1.f / l;
    }
#pragma unroll
    for (int nt2 = 0; nt2 < 2; ++nt2)
#pragma unroll
      for (int r = 0; r < 4; ++r)
        bufx0[(mt * 16 + quad * 4 + r) * 264 + eh + nt2 * 16 + l16] =
            f2bf(o_acc[mt][nt2][r] * invl[r]);
  }
  __syncthreads();

  // ---------------- GEMM1: proj = AO @ w_out^T + b_out -> sK0 (bf16)
#pragma unroll
  for (int mt = 0; mt < 2; ++mt) {
    bf16x8 a8[8];
#pragma unroll
    for (int k = 0; k < 8; ++k)
      a8[k] = *(const bf16x8*)&bufx0[(mt * 16 + l16) * 264 + k * 32 + quad * 8];
#pragma unroll
    for (int nt2 = 0; nt2 < 2; ++nt2) {
      const int e0 = w * 32 + nt2 * 16;
      floatx4 acc = fzero;
#pragma unroll
      for (int k = 0; k < 8; ++k) {
        bf16x8 b8 = *(const bf16x8*)&wobf[(c * 256 + e0 + l16) * DIM + k * 32 + quad * 8];
        acc = __builtin_amdgcn_mfma_f32_16x16x32_bf16(a8[k], b8, acc, 0, 0, 0);
      }
      const float bias = b_out[c * 256 + e0 + l16];
#pragma unroll
      for (int r = 0; r < 4; ++r)
        sK0[(mt * 16 + quad * 4 + r) * 264 + e0 + l16] = f2bf(acc[r] + bias);
    }
  }
  __syncthreads();

  // ---------------- GEMM2: out = proj @ w_fuse^T + b_fuse + x
#pragma unroll
  for (int mt = 0; mt < 2; ++mt) {
    bf16x8 a8[8];
#pragma unroll
    for (int k = 0; k < 8; ++k)
      a8[k] = *(const bf16x8*)&sK0[(mt * 16 + l16) * 264 + k * 32 + quad * 8];
#pragma unroll
    for (int nt2 = 0; nt2 < 2; ++nt2) {
      const int e0 = w * 32 + nt2 * 16;
      floatx4 acc = fzero;
#pragma unroll
      for (int k = 0; k < 8; ++k) {
        bf16x8 b8 = *(const bf16x8*)&wfbf[(e0 + l16) * DIM + k * 32 + quad * 8];
        acc = __builtin_amdgcn_mfma_f32_16x16x32_bf16(a8[k], b8, acc, 0, 0, 0);
      }
      const float bfu = b_fuse[e0 + l16];
#pragma unroll
      for (int r = 0; r < 4; ++r) {
        const int row = mt * 16 + quad * 4 + r;
        if (row < CC) {
          const int gp = (b * NPOS + c * CC + row) * DIM + e0 + l16;
          out[gp] = acc[r] + bfu + xf[gp];
        }
      }
    }
  }
}

extern "C" void kernel_launch(void* const* d_in, const int* in_sizes, int n_in,
                              void* d_out, int out_size, void* d_ws, size_t ws_size,
                              hipStream_t stream) {
  const float* x      = (const float*)d_in[0];
  const float* w_in   = (const float*)d_in[1];
  const float* b_in   = (const float*)d_in[2];
  const float* w_out  = (const float*)d_in[3];
  const float* b_out  = (const float*)d_in[4];
  const float* w_fuse = (const float*)d_in[5];
  const float* b_fuse = (const float*)d_in[6];
  float* out = (float*)d_out;

  if (ws_size < (size_t)16384000) return;  // 16.38 MB bf16 scratch (validated bound)

  unsigned short* ws = (unsigned short*)d_ws;
  unsigned short* x_bf  = ws;              // 32*384*256   = 3,145,728
  unsigned short* wi_bf = ws + 3145728;    // 19*768*256   = 3,735,552
  unsigned short* wo_bf = ws + 6881280;    // 19*256*256   = 1,245,184
  unsigned short* wf_bf = ws + 8126464;    // 256*256      = 65,536

  conv_all_kernel<<<8000, 256, 0, stream>>>(x, w_in, w_out, w_fuse, ws);

  (void)hipFuncSetAttribute((const void*)cgca_kernel,
                            hipFuncAttributeMaxDynamicSharedMemorySize, LDS_BYTES);
  cgca_kernel<<<608, 512, LDS_BYTES, stream>>>(x, b_in, b_out, b_fuse, x_bf, wi_bf,
                                               wo_bf, wf_bf, out);
}

// Round 11
// 253.589 us; speedup vs baseline: 2.0146x; 1.1241x over previous
//
#include <hip/hip_runtime.h>

#define CC 19
#define NPOS 361
#define NPAD 384
#define DIM 256
#define TKEY 32
#define NTILES 12

// LDS (bytes): bufx0/bufx1 32x264 bf16 double-buffered x tile = 33792 total.
// Epilogue reuse: bufx0 = AO (bf16), bufx1 = sL (l values, first 1KB) then T.
#define LDS_BYTES 33792

using bf16x8 = __attribute__((ext_vector_type(8))) short;
using f16x4  = __attribute__((ext_vector_type(4))) _Float16;
using floatx4 = __attribute__((ext_vector_type(4))) float;
using uintx2 = __attribute__((ext_vector_type(2))) unsigned int;

__device__ __forceinline__ unsigned short f2bf(float f) {
  unsigned u = __builtin_bit_cast(unsigned, f);
  u += 0x7fffu + ((u >> 16) & 1u);
  return (unsigned short)(u >> 16);
}

__device__ __forceinline__ f16x4 pack4h(float a, float b, float c2, float d) {
  const auto h01 = __builtin_amdgcn_cvt_pkrtz(a, b);
  const auto h23 = __builtin_amdgcn_cvt_pkrtz(c2, d);
  uintx2 uv = {__builtin_bit_cast(unsigned, h01), __builtin_bit_cast(unsigned, h23)};
  return __builtin_bit_cast(f16x4, uv);
}

// fused conversion: x (zero-padded 361->384 rows) + all weights, f32 -> bf16
// (R8 lesson: inline conversion in the hot kernel raises the liveset -> spills)
__global__ void conv_all_kernel(const float* __restrict__ x,
                                const float* __restrict__ w_in,
                                const float* __restrict__ w_out,
                                const float* __restrict__ w_fuse,
                                unsigned short* __restrict__ ws) {
  const int j = blockIdx.x * 256 + threadIdx.x;
  float4 v = make_float4(0.f, 0.f, 0.f, 0.f);
  unsigned short* dst;
  if (j < 786432) {
    const int row = j >> 6;
    const int off = (j & 63) << 2;
    const int b = row / NPAD;
    const int r = row - b * NPAD;
    if (r < NPOS) v = *(const float4*)&x[(b * NPOS + r) * DIM + off];
    dst = &ws[row * DIM + off];
  } else if (j < 1720320) {
    const int k = j - 786432;
    v = *(const float4*)&w_in[k << 2];
    dst = &ws[3145728 + (k << 2)];
  } else if (j < 2031616) {
    const int k = j - 1720320;
    v = *(const float4*)&w_out[k << 2];
    dst = &ws[6881280 + (k << 2)];
  } else {
    const int k = j - 2031616;
    v = *(const float4*)&w_fuse[k << 2];
    dst = &ws[8126464 + (k << 2)];
  }
  ushort4 o;
  o.x = f2bf(v.x); o.y = f2bf(v.y); o.z = f2bf(v.z); o.w = f2bf(v.w);
  *(ushort4*)dst = o;
}

// launch_bounds (512,2): cap 256 regs -> natural ~240 liveset fits, no spills
// (R2/R4/R8: capping below liveset spills at 3x cost). Occupancy is pinned at
// 2 waves/SIMD by unified regs -> minimize the per-tile serial chain instead:
// K/V/Q/P all stay in registers via MFMA operand-order layout chaining.
__launch_bounds__(512, 2)
__global__ void cgca_kernel(const float* __restrict__ xf,
                            const float* __restrict__ b_in,
                            const float* __restrict__ b_out,
                            const float* __restrict__ b_fuse,
                            const unsigned short* __restrict__ xbf,
                            const unsigned short* __restrict__ wibf,
                            const unsigned short* __restrict__ wobf,
                            const unsigned short* __restrict__ wfbf,
                            float* __restrict__ out) {
  // XCD-aware swizzle: same channel's 32 batches contiguous on one XCD.
  const int bid = blockIdx.x;
  const int xcd = bid & 7;
  const int slot = bid >> 3;
  int c, b;
  if (slot < 64) {
    c = ((slot >> 5) << 3) + xcd;   // channels 0..15
    b = slot & 31;
  } else {
    const int widx = ((slot - 64) << 3) + xcd;  // 0..95
    c = 16 + (widx >> 5);           // channels 16..18
    b = widx & 31;
  }

  const int tid = threadIdx.x;
  const int w = tid >> 6;        // wave 0..7 == head index
  const int lane = tid & 63;
  const int quad = lane >> 4;
  const int l16 = lane & 15;
  const int eh = w * 32;

  extern __shared__ char smem[];
  unsigned short* bufx0 = (unsigned short*)(smem);
  unsigned short* bufx1 = (unsigned short*)(smem + 16896);
  float* sL = (float*)(smem + 16896);  // 8 waves x 32 floats; dead before T written

  const float scale = 0.17677669529663687f;  // 1/sqrt(32)
  const floatx4 fzero = {0.f, 0.f, 0.f, 0.f};

  // ---------------- Q phase: qf[mt][echunk] = B-frag of transposed scores.
  // MFMA(wQ as A, xq as B) -> D[m=e][n=q]: lane q=l16 (col), e=quad*4+r (row).
  f16x4 qf[2][2];
  {
    bf16x8 wq[2][8];
#pragma unroll
    for (int m4 = 0; m4 < 2; ++m4)
#pragma unroll
      for (int k = 0; k < 8; ++k)
        wq[m4][k] = *(const bf16x8*)&wibf[(c * 768 + eh + m4 * 16 + l16) * DIM + k * 32 + quad * 8];
    float bq[2][4];
#pragma unroll
    for (int m4 = 0; m4 < 2; ++m4) {
      const float4 bv4 = *(const float4*)&b_in[c * 768 + eh + m4 * 16 + quad * 4];
      bq[m4][0] = bv4.x; bq[m4][1] = bv4.y; bq[m4][2] = bv4.z; bq[m4][3] = bv4.w;
    }
#pragma unroll
    for (int mt = 0; mt < 2; ++mt) {
      const int xrow = b * NPAD + c * CC + mt * 16 + l16;  // zero-padded rows
      bf16x8 xq[8];
#pragma unroll
      for (int k = 0; k < 8; ++k)
        xq[k] = *(const bf16x8*)&xbf[xrow * DIM + k * 32 + quad * 8];
#pragma unroll
      for (int m4 = 0; m4 < 2; ++m4) {
        floatx4 acc = fzero;
#pragma unroll
        for (int k = 0; k < 8; ++k)
          acc = __builtin_amdgcn_mfma_f32_16x16x32_bf16(wq[m4][k], xq[k], acc, 0, 0, 0);
        qf[mt][m4] = pack4h((acc[0] + bq[m4][0]) * scale, (acc[1] + bq[m4][1]) * scale,
                            (acc[2] + bq[m4][2]) * scale, (acc[3] + bq[m4][3]) * scale);
      }
    }
  }

  // ---------------- head-local K/V weight slabs -> registers (loop-invariant)
  // wK rows 256+eh..+32 as A-frag; wV rows 512+eh..+32 as B-frag (same layout).
  bf16x8 wk[2][8], wv[2][8];
#pragma unroll
  for (int m4 = 0; m4 < 2; ++m4)
#pragma unroll
    for (int k = 0; k < 8; ++k) {
      wk[m4][k] =
          *(const bf16x8*)&wibf[(c * 768 + 256 + eh + m4 * 16 + l16) * DIM + k * 32 + quad * 8];
      wv[m4][k] =
          *(const bf16x8*)&wibf[(c * 768 + 512 + eh + m4 * 16 + l16) * DIM + k * 32 + quad * 8];
    }
  float bk[2][4];
#pragma unroll
  for (int m4 = 0; m4 < 2; ++m4) {
    const float4 bv4 = *(const float4*)&b_in[c * 768 + 256 + eh + m4 * 16 + quad * 4];
    bk[m4][0] = bv4.x; bk[m4][1] = bv4.y; bk[m4][2] = bv4.z; bk[m4][3] = bv4.w;
  }
  float bV[2];
#pragma unroll
  for (int ne = 0; ne < 2; ++ne) bV[ne] = b_in[c * 768 + 512 + eh + ne * 16 + l16];

  // stage x tile 0 -> bufx0
#pragma unroll
  for (int it = 0; it < 2; ++it) {
    const int cc2 = tid + it * 512;
    const int row = cc2 >> 5;
    const int col = (cc2 & 31) * 8;
    *(bf16x8*)&bufx0[row * 264 + col] = *(const bf16x8*)&xbf[(b * NPAD + row) * DIM + col];
  }

  floatx4 o_acc[2][2];           // [mt][echunk], D[m=q][n=e]: q=quad*4+r, e=l16
  float lsum[2] = {0.f, 0.f};    // per-lane partial denom (q=l16, keys of this quad)
#pragma unroll
  for (int mt = 0; mt < 2; ++mt)
#pragma unroll
    for (int ne = 0; ne < 2; ++ne) o_acc[mt][ne] = fzero;

  __syncthreads();  // x(0) staged

  for (int t = 0; t < NTILES; ++t) {
    const int t0 = t * TKEY;
    unsigned short* bx  = (t & 1) ? bufx1 : bufx0;
    unsigned short* bxn = (t & 1) ? bufx0 : bufx1;

    // stage x(t+1) -> other buffer (its readers are past the t-1 barrier)
    if (t + 1 < NTILES) {
#pragma unroll
      for (int it = 0; it < 2; ++it) {
        const int cc2 = tid + it * 512;
        const int row = cc2 >> 5;
        const int col = (cc2 & 31) * 8;
        *(bf16x8*)&bxn[row * 264 + col] =
            *(const bf16x8*)&xbf[(b * NPAD + t0 + TKEY + row) * DIM + col];
      }
    }

    // ---------------- K/V projection, all-register outputs
    // aK[echunk][keytile] = MFMA(wK, x): lane key=l16, e=quad*4+r
    // aV[keytile][echunk] = MFMA(x, wV): lane e=l16, key=quad*4+r
    floatx4 aK[2][2], aV[2][2];
#pragma unroll
    for (int i = 0; i < 2; ++i)
#pragma unroll
      for (int j = 0; j < 2; ++j) { aK[i][j] = fzero; aV[i][j] = fzero; }
#pragma unroll
    for (int k = 0; k < 8; ++k) {
      bf16x8 xfr[2];
#pragma unroll
      for (int n4 = 0; n4 < 2; ++n4)
        xfr[n4] = *(const bf16x8*)&bx[(n4 * 16 + l16) * 264 + k * 32 + quad * 8];
#pragma unroll
      for (int m4 = 0; m4 < 2; ++m4)
#pragma unroll
        for (int n4 = 0; n4 < 2; ++n4) {
          aK[m4][n4] = __builtin_amdgcn_mfma_f32_16x16x32_bf16(wk[m4][k], xfr[n4], aK[m4][n4], 0, 0, 0);
          aV[n4][m4] = __builtin_amdgcn_mfma_f32_16x16x32_bf16(xfr[n4], wv[m4][k], aV[n4][m4], 0, 0, 0);
        }
    }
    __syncthreads();  // the ONE barrier: all proj reads of bx done; rest is register-only

    // convert to MFMA-ready f16 fragments (+bias)
    f16x4 kf[2][2];  // [keytile][echunk] = A-frag of transposed scores
    f16x4 vf[2][2];  // [keytile][echunk] = B-frag of PV
#pragma unroll
    for (int kt = 0; kt < 2; ++kt)
#pragma unroll
      for (int ec = 0; ec < 2; ++ec) {
        kf[kt][ec] = pack4h(aK[ec][kt][0] + bk[ec][0], aK[ec][kt][1] + bk[ec][1],
                            aK[ec][kt][2] + bk[ec][2], aK[ec][kt][3] + bk[ec][3]);
        vf[kt][ec] = pack4h(aV[kt][ec][0] + bV[ec], aV[kt][ec][1] + bV[ec],
                            aV[kt][ec][2] + bV[ec], aV[kt][ec][3] + bV[ec]);
      }

    // ---------------- scores (transposed) + mask + exp + PV, all in registers
#pragma unroll
    for (int mt = 0; mt < 2; ++mt) {
      const unsigned q = (unsigned)(mt * 16 + l16);
      f16x4 pf[2];
#pragma unroll
      for (int kt = 0; kt < 2; ++kt) {
        floatx4 s = __builtin_amdgcn_mfma_f32_16x16x16f16(kf[kt][0], qf[mt][0], fzero, 0, 0, 0);
        s = __builtin_amdgcn_mfma_f32_16x16x16f16(kf[kt][1], qf[mt][1], s, 0, 0, 0);
        // lane: q=l16 (col), key = t0 + kt*16 + quad*4 + r (row)
        const int kbase = t0 + kt * 16 + quad * 4;
        float p[4];
#pragma unroll
        for (int r = 0; r < 4; ++r) {
          const int kabs = kbase + r;
          const unsigned ki = ((unsigned)kabs * 110377u) >> 21;  // kabs/19, kabs<=383
          const unsigned kj = (unsigned)kabs - ki * 19u;
          const bool ok = (kabs < NPOS) &&
                          (ki == (unsigned)c || kj == (unsigned)c || ki == q || kj == q);
          p[r] = ok ? __expf(s[r]) : 0.f;
        }
        lsum[mt] += (p[0] + p[1]) + (p[2] + p[3]);
        pf[kt] = pack4h(p[0], p[1], p[2], p[3]);
      }
#pragma unroll
      for (int kt = 0; kt < 2; ++kt)
#pragma unroll
        for (int ne = 0; ne < 2; ++ne)
          o_acc[mt][ne] =
              __builtin_amdgcn_mfma_f32_16x16x16f16(pf[kt], vf[kt][ne], o_acc[mt][ne], 0, 0, 0);
    }
  }  // tile loop

  // ---------------- denom: reduce lsum across quads (q=l16 fixed), publish per wave
#pragma unroll
  for (int mt = 0; mt < 2; ++mt) {
    lsum[mt] += __shfl_xor(lsum[mt], 16);
    lsum[mt] += __shfl_xor(lsum[mt], 32);
  }
  if (lane < 16) {
    sL[w * 32 + lane] = lsum[0];
    sL[w * 32 + 16 + lane] = lsum[1];
  }
  // wave-local LDS round-trip (lgkmcnt-ordered), no barrier needed
  float invl[2][4];
#pragma unroll
  for (int mt = 0; mt < 2; ++mt)
#pragma unroll
    for (int r = 0; r < 4; ++r)
      invl[mt][r] = 1.f / sL[w * 32 + mt * 16 + quad * 4 + r];

  // ---------------- AO -> bufx0 (bf16): row q = mt*16+quad*4+r, col = eh+ne*16+l16
#pragma unroll
  for (int mt = 0; mt < 2; ++mt)
#pragma unroll
    for (int ne = 0; ne < 2; ++ne)
#pragma unroll
      for (int r = 0; r < 4; ++r)
        bufx0[(mt * 16 + quad * 4 + r) * 264 + eh + ne * 16 + l16] =
            f2bf(o_acc[mt][ne][r] * invl[mt][r]);
  __syncthreads();

  // ---------------- GEMM1: proj = AO @ w_out^T + b_out -> bufx1 (bf16)
#pragma unroll
  for (int mt = 0; mt < 2; ++mt) {
    bf16x8 a8[8];
#pragma unroll
    for (int k = 0; k < 8; ++k)
      a8[k] = *(const bf16x8*)&bufx0[(mt * 16 + l16) * 264 + k * 32 + quad * 8];
#pragma unroll
    for (int nt2 = 0; nt2 < 2; ++nt2) {
      const int e0 = w * 32 + nt2 * 16;
      floatx4 acc = fzero;
#pragma unroll
      for (int k = 0; k < 8; ++k) {
        bf16x8 b8 = *(const bf16x8*)&wobf[(c * 256 + e0 + l16) * DIM + k * 32 + quad * 8];
        acc = __builtin_amdgcn_mfma_f32_16x16x32_bf16(a8[k], b8, acc, 0, 0, 0);
      }
      const float bias = b_out[c * 256 + e0 + l16];
#pragma unroll
      for (int r = 0; r < 4; ++r)
        bufx1[(mt * 16 + quad * 4 + r) * 264 + e0 + l16] = f2bf(acc[r] + bias);
    }
  }
  __syncthreads();

  // ---------------- GEMM2: out = proj @ w_fuse^T + b_fuse + x
#pragma unroll
  for (int mt = 0; mt < 2; ++mt) {
    bf16x8 a8[8];
#pragma unroll
    for (int k = 0; k < 8; ++k)
      a8[k] = *(const bf16x8*)&bufx1[(mt * 16 + l16) * 264 + k * 32 + quad * 8];
#pragma unroll
    for (int nt2 = 0; nt2 < 2; ++nt2) {
      const int e0 = w * 32 + nt2 * 16;
      floatx4 acc = fzero;
#pragma unroll
      for (int k = 0; k < 8; ++k) {
        bf16x8 b8 = *(const bf16x8*)&wfbf[(e0 + l16) * DIM + k * 32 + quad * 8];
        acc = __builtin_amdgcn_mfma_f32_16x16x32_bf16(a8[k], b8, acc, 0, 0, 0);
      }
      const float bfu = b_fuse[e0 + l16];
#pragma unroll
      for (int r = 0; r < 4; ++r) {
        const int row = mt * 16 + quad * 4 + r;
        if (row < CC) {
          const int gp = (b * NPOS + c * CC + row) * DIM + e0 + l16;
          out[gp] = acc[r] + bfu + xf[gp];
        }
      }
    }
  }
}

extern "C" void kernel_launch(void* const* d_in, const int* in_sizes, int n_in,
                              void* d_out, int out_size, void* d_ws, size_t ws_size,
                              hipStream_t stream) {
  const float* x      = (const float*)d_in[0];
  const float* w_in   = (const float*)d_in[1];
  const float* b_in   = (const float*)d_in[2];
  const float* w_out  = (const float*)d_in[3];
  const float* b_out  = (const float*)d_in[4];
  const float* w_fuse = (const float*)d_in[5];
  const float* b_fuse = (const float*)d_in[6];
  float* out = (float*)d_out;

  if (ws_size < (size_t)16384000) return;  // 16.38 MB bf16 scratch (validated bound)

  unsigned short* ws = (unsigned short*)d_ws;
  unsigned short* x_bf  = ws;              // 32*384*256   = 3,145,728
  unsigned short* wi_bf = ws + 3145728;    // 19*768*256   = 3,735,552
  unsigned short* wo_bf = ws + 6881280;    // 19*256*256   = 1,245,184
  unsigned short* wf_bf = ws + 8126464;    // 256*256      = 65,536

  conv_all_kernel<<<8000, 256, 0, stream>>>(x, w_in, w_out, w_fuse, ws);

  (void)hipFuncSetAttribute((const void*)cgca_kernel,
                            hipFuncAttributeMaxDynamicSharedMemorySize, LDS_BYTES);
  cgca_kernel<<<608, 512, LDS_BYTES, stream>>>(x, b_in, b_out, b_fuse, x_bf, wi_bf,
                                               wo_bf, wf_bf, out);
}